// Round 2
// baseline (11244.912 us; speedup 1.0000x reference)
//
#include <hip/hip_runtime.h>
#include <hip/hip_bf16.h>

// Problem constants (fixed by setup_inputs; iters_to_do is always 16).
#define BB 32
#define WW 384
#define LL 512
#define ITERS 16
#define NPB (WW * LL)  // elems per batch for LayerNorm (196608)

// w [COUT][CIN_real][3] (fp32) -> wT [CINP][3][COUT] (fp32), zero-padded rows
__global__ void wtrans(const float* __restrict__ w, float* __restrict__ wT,
                       int COUT, int CIN_real, int CINP) {
    int i = blockIdx.x * 256 + threadIdx.x;
    int total = CINP * 3 * COUT;
    if (i >= total) return;
    int co = i % COUT;
    int k = (i / COUT) % 3;
    int c = i / (3 * COUT);
    float v = 0.f;
    if (c < CIN_real) v = w[(co * CIN_real + c) * 3 + k];
    wT[i] = v;
}

// it0 = relu(conv1d(x, proj_w)), one thread per (b, co, l)
__global__ void proj_relu(const float* __restrict__ xf,
                          const float* __restrict__ wp,
                          float* __restrict__ it0) {
    int i = blockIdx.x * 256 + threadIdx.x;  // over BB*WW*LL
    int l = i % LL;
    int co = (i / LL) % WW;
    int b = i / (LL * WW);
    float x0 = (l > 0) ? xf[b * LL + l - 1] : 0.f;
    float x1 = xf[b * LL + l];
    float x2 = (l < LL - 1) ? xf[b * LL + l + 1] : 0.f;
    float acc = wp[co * 3 + 0] * x0 + wp[co * 3 + 1] * x1 + wp[co * 3 + 2] * x2;
    it0[i] = fmaxf(acc, 0.f);
}

// Partial sums for LayerNorm over (C,L): grid = 32 batches x 8 slices
__global__ __launch_bounds__(256) void ln_stats(const float* __restrict__ it,
                                                float* __restrict__ part) {
    int b = blockIdx.x >> 3, sl = blockIdx.x & 7;
    const float4* p = (const float4*)(it + (size_t)b * NPB + sl * (NPB / 8));
    float s = 0.f, sq = 0.f;
    for (int i = threadIdx.x; i < NPB / 8 / 4; i += 256) {
        float4 v = p[i];
        s += v.x + v.y + v.z + v.w;
        sq += v.x * v.x + v.y * v.y + v.z * v.z + v.w * v.w;
    }
    #pragma unroll
    for (int o = 32; o > 0; o >>= 1) {
        s += __shfl_down(s, o);
        sq += __shfl_down(sq, o);
    }
    __shared__ float ls[4], lq[4];
    int wv = threadIdx.x >> 6;
    if ((threadIdx.x & 63) == 0) { ls[wv] = s; lq[wv] = sq; }
    __syncthreads();
    if (threadIdx.x == 0) {
        s = ls[0] + ls[1] + ls[2] + ls[3];
        sq = lq[0] + lq[1] + lq[2] + lq[3];
        part[(b * 8 + sl) * 2] = s;
        part[(b * 8 + sl) * 2 + 1] = sq;
    }
}

// Generic k=3 SAME conv, tile [Cout=32 x L=64] per block, 4 waves.
// MODE 0: out = relu(c).  MODE 1 (energy): out = xl - 0.1*c - 0.2*relu(xl),
//   xl = LN(in) computed from `part` partial sums; channel WW of the conv
//   input (CINTOT=385) is the extra x channel from `xf`.
template <int CINTOT, int COUT, int MODE>
__global__ __launch_bounds__(256) void conv3(
    const float* __restrict__ in,    // [BB][WW][LL]
    const float* __restrict__ xf,    // [BB][LL] (only CINTOT>WW)
    const float* __restrict__ wT,    // [CINP][3][COUT]
    const float* __restrict__ part,  // LN partials (MODE 1)
    float* __restrict__ out)         // [BB][COUT][LL]
{
    constexpr int CHUNKS = (CINTOT + 15) / 16;
    int lt = blockIdx.x & 7;
    int ct = (blockIdx.x >> 3) % (COUT / 32);
    int b = blockIdx.x / (8 * (COUT / 32));
    int tid = threadIdx.x;
    int li = tid & 63;
    // force wave-uniform so weight reads become scalar (s_load) loads
    int wv = __builtin_amdgcn_readfirstlane(tid >> 6);
    int l0 = lt * 64;
    const float* inb = in + (size_t)b * (WW * LL);

    __shared__ float Xs[16][66];
    float acc[8];
    #pragma unroll
    for (int j = 0; j < 8; j++) acc[j] = 0.f;

    for (int cin0 = 0; cin0 < CHUNKS * 16; cin0 += 16) {
        // stage X chunk (with halo, zero-padded) into LDS
        for (int idx = tid; idx < 16 * 66; idx += 256) {
            int ci = idx / 66, lo = idx % 66;
            int c = cin0 + ci;
            int l = l0 + lo - 1;
            float v = 0.f;
            if (l >= 0 && l < LL) {
                if (c < WW) v = inb[c * LL + l];
                else if (CINTOT > WW && c == WW) v = xf[b * LL + l];
            }
            Xs[ci][lo] = v;
        }
        __syncthreads();
        int cbase = ct * 32 + wv * 8;
        #pragma unroll
        for (int ci = 0; ci < 16; ci++) {
            float x0 = Xs[ci][li];
            float x1 = Xs[ci][li + 1];
            float x2 = Xs[ci][li + 2];
            const float* wp = wT + (size_t)(cin0 + ci) * 3 * COUT + cbase;
            #pragma unroll
            for (int j = 0; j < 8; j++) {
                acc[j] = fmaf(wp[j], x0, acc[j]);
                acc[j] = fmaf(wp[COUT + j], x1, acc[j]);
                acc[j] = fmaf(wp[2 * COUT + j], x2, acc[j]);
            }
        }
        __syncthreads();
    }

    int l = l0 + li;
    if (MODE == 0) {
        #pragma unroll
        for (int j = 0; j < 8; j++) {
            int co = ct * 32 + wv * 8 + j;
            out[((size_t)b * COUT + co) * LL + l] = fmaxf(acc[j], 0.f);
        }
    } else {
        float s = 0.f, sq = 0.f;
        #pragma unroll
        for (int p = 0; p < 8; p++) {
            s += part[(b * 8 + p) * 2];
            sq += part[(b * 8 + p) * 2 + 1];
        }
        float mu = s / (float)NPB;
        float var = sq / (float)NPB - mu * mu;
        float rs = rsqrtf(var + 1e-5f);
        #pragma unroll
        for (int j = 0; j < 8; j++) {
            int co = ct * 32 + wv * 8 + j;
            float itv = inb[co * LL + l];
            float xl = (itv - mu) * rs;
            float nv = xl - 0.1f * acc[j] - 0.2f * fmaxf(xl, 0.f);
            out[((size_t)b * COUT + co) * LL + l] = nv;
        }
    }
}

// Final 192->2 conv, writes fp32 output at iteration t.
__global__ __launch_bounds__(256) void h3_conv(const float* __restrict__ a2,
                                               const float* __restrict__ w3,
                                               float* __restrict__ out, int t) {
    __shared__ float ws3[2 * 192 * 3];
    int tid = threadIdx.x;
    for (int i = tid; i < 2 * 192 * 3; i += 256) ws3[i] = w3[i];
    __syncthreads();
    int b = blockIdx.x >> 1;
    int l = (blockIdx.x & 1) * 256 + tid;
    const float* ab = a2 + (size_t)b * 192 * LL;
    float a0 = 0.f, a1 = 0.f;
    for (int c = 0; c < 192; c++) {
        float x0 = (l > 0) ? ab[c * LL + l - 1] : 0.f;
        float x1 = ab[c * LL + l];
        float x2 = (l < LL - 1) ? ab[c * LL + l + 1] : 0.f;
        a0 += ws3[0 * 576 + c * 3 + 0] * x0 + ws3[0 * 576 + c * 3 + 1] * x1 +
              ws3[0 * 576 + c * 3 + 2] * x2;
        a1 += ws3[1 * 576 + c * 3 + 0] * x0 + ws3[1 * 576 + c * 3 + 1] * x1 +
              ws3[1 * 576 + c * 3 + 2] * x2;
    }
    out[(((size_t)b * ITERS + t) * 2 + 0) * LL + l] = a0;
    out[(((size_t)b * ITERS + t) * 2 + 1) * LL + l] = a1;
}

extern "C" void kernel_launch(void* const* d_in, const int* in_sizes, int n_in,
                              void* d_out, int out_size, void* d_ws, size_t ws_size,
                              hipStream_t stream) {
    const float* x = (const float*)d_in[0];        // [32][1][512] fp32
    // d_in[1] = iters_to_do (int, always 16 for this problem)
    const float* proj_w = (const float*)d_in[2];   // [384][1][3]
    const float* op_w = (const float*)d_in[3];     // [384][385][3]
    const float* h1_w = (const float*)d_in[4];     // [384][384][3]
    const float* h2_w = (const float*)d_in[5];     // [192][384][3]
    const float* h3_w = (const float*)d_in[6];     // [2][192][3]
    float* out = (float*)d_out;                    // [32][16][2][512] fp32

    float* ws0 = (float*)d_ws;
    size_t off = 0;
    auto alloc = [&](size_t n) {
        float* p = ws0 + off;
        off += (n + 63) & ~(size_t)63;
        return p;
    };
    float* itA = alloc((size_t)BB * WW * LL);
    float* itB = alloc((size_t)BB * WW * LL);
    float* a1 = alloc((size_t)BB * WW * LL);
    float* a2 = alloc((size_t)BB * (WW / 2) * LL);
    float* wTop = alloc((size_t)400 * 3 * WW);
    float* wTh1 = alloc((size_t)384 * 3 * WW);
    float* wTh2 = alloc((size_t)384 * 3 * (WW / 2));
    float* part = alloc((size_t)BB * 8 * 2);
    if (off * sizeof(float) > ws_size) return;  // workspace too small

    wtrans<<<(400 * 3 * 384 + 255) / 256, 256, 0, stream>>>(op_w, wTop, 384, 385, 400);
    wtrans<<<(384 * 3 * 384 + 255) / 256, 256, 0, stream>>>(h1_w, wTh1, 384, 384, 384);
    wtrans<<<(384 * 3 * 192 + 255) / 256, 256, 0, stream>>>(h2_w, wTh2, 192, 384, 384);
    proj_relu<<<(BB * WW * LL) / 256, 256, 0, stream>>>(x, proj_w, itA);

    float* cur = itA;
    float* nxt = itB;
    for (int t = 0; t < ITERS; t++) {
        ln_stats<<<BB * 8, 256, 0, stream>>>(cur, part);
        conv3<385, 384, 1><<<32 * 12 * 8, 256, 0, stream>>>(cur, x, wTop, part, nxt);
        conv3<384, 384, 0><<<32 * 12 * 8, 256, 0, stream>>>(nxt, nullptr, wTh1, nullptr, a1);
        conv3<384, 192, 0><<<32 * 6 * 8, 256, 0, stream>>>(a1, nullptr, wTh2, nullptr, a2);
        h3_conv<<<BB * 2, 256, 0, stream>>>(a2, h3_w, out, t);
        float* tmp = cur; cur = nxt; nxt = tmp;
    }
}

// Round 3
// 4245.736 us; speedup vs baseline: 2.6485x; 2.6485x over previous
//
#include <hip/hip_runtime.h>
#include <hip/hip_bf16.h>

#define BB 32
#define WW 384
#define LL 512
#define ITERS 16
#define NPB (WW * LL)
#define LROWS 514           // 1 + 512 + 1 halo rows
#define CIP 416             // padded ci for it/cat buffers (13 K-chunks of 32)

typedef __attribute__((ext_vector_type(8))) short bf16x8;
typedef __attribute__((ext_vector_type(4))) float f32x4;

// ---------------------------------------------------------------- prep
// op_w [384][385][3] -> wh/wl [3][384][416] (hi/lo bf16 split, zero-padded ci)
__global__ void wsplit_op(const float* __restrict__ w, short* __restrict__ wh,
                          short* __restrict__ wl) {
    int i = blockIdx.x * 256 + threadIdx.x;
    if (i >= 3 * 384 * CIP) return;
    int ci = i % CIP, co = (i / CIP) % 384, tap = i / (CIP * 384);
    float v = (ci < 385) ? w[(co * 385 + ci) * 3 + tap] : 0.f;
    __hip_bfloat16 h = __float2bfloat16(v);
    float lo = v - __bfloat162float(h);
    ((__hip_bfloat16*)wh)[i] = h;
    ((__hip_bfloat16*)wl)[i] = __float2bfloat16(lo);
}

// generic hi-only: src [CO_real][CIN][3] -> dst [3][COD][CIN] (co>=CO_real -> 0)
__global__ void wsplit_h(const float* __restrict__ w, short* __restrict__ wh,
                         int COD, int CIN, int CO_real) {
    int i = blockIdx.x * 256 + threadIdx.x;
    if (i >= 3 * COD * CIN) return;
    int ci = i % CIN, co = (i / CIN) % COD, tap = i / (CIN * COD);
    float v = (co < CO_real) ? w[(co * CIN + ci) * 3 + tap] : 0.f;
    ((__hip_bfloat16*)wh)[i] = __float2bfloat16(v);
}

// zero halo rows of it buffers + a1; write x (hi/lo) into channel 384 of both
// it ping-pong buffers, zero channels 385..415.
__global__ void init_rows(const float* __restrict__ x, short* itAh, short* itAl,
                          short* itBh, short* itBl, short* a1) {
    int row = blockIdx.x % LROWS, b = blockIdx.x / LROWS;
    int tid = threadIdx.x;
    size_t base = ((size_t)b * LROWS + row) * CIP;
    size_t base1 = ((size_t)b * LROWS + row) * WW;
    if (row == 0 || row == LROWS - 1) {
        for (int i = tid; i < CIP; i += 64) {
            itAh[base + i] = 0; itAl[base + i] = 0;
            itBh[base + i] = 0; itBl[base + i] = 0;
        }
        for (int i = tid; i < WW; i += 64) a1[base1 + i] = 0;
    } else {
        if (tid < 32) {
            int ci = WW + tid;
            short h = 0, l = 0;
            if (ci == WW) {
                float xv = x[b * LL + row - 1];
                __hip_bfloat16 xh = __float2bfloat16(xv);
                float xlo = xv - __bfloat162float(xh);
                h = *(short*)&xh;
                __hip_bfloat16 xl2 = __float2bfloat16(xlo);
                l = *(short*)&xl2;
            }
            itAh[base + ci] = h; itAl[base + ci] = l;
            itBh[base + ci] = h; itBl[base + ci] = l;
        }
    }
}

__global__ void zero_part(float* part, int n) {
    int i = blockIdx.x * 256 + threadIdx.x;
    if (i < n) part[i] = 0.f;
}

// it0 = relu(conv1d(x, proj_w)) -> itA hi/lo (channel-last) + LN stats -> part[0]
__global__ __launch_bounds__(256) void proj_relu(const float* __restrict__ x,
                                                 const float* __restrict__ wp,
                                                 short* __restrict__ oh,
                                                 short* __restrict__ ol,
                                                 float* __restrict__ part) {
    int b = blockIdx.y;
    int idx = blockIdx.x * 256 + threadIdx.x;  // over 512*384
    int l = idx / WW, co = idx % WW;
    float x0 = (l > 0) ? x[b * LL + l - 1] : 0.f;
    float x1 = x[b * LL + l];
    float x2 = (l < LL - 1) ? x[b * LL + l + 1] : 0.f;
    float v = fmaxf(wp[co * 3] * x0 + wp[co * 3 + 1] * x1 + wp[co * 3 + 2] * x2, 0.f);
    size_t o = ((size_t)b * LROWS + l + 1) * CIP + co;
    __hip_bfloat16 h = __float2bfloat16(v);
    float lo = v - __bfloat162float(h);
    oh[o] = *(short*)&h;
    __hip_bfloat16 l2 = __float2bfloat16(lo);
    ol[o] = *(short*)&l2;
    // stats
    float s = v, sq = v * v;
    #pragma unroll
    for (int off = 32; off > 0; off >>= 1) {
        s += __shfl_down(s, off);
        sq += __shfl_down(sq, off);
    }
    __shared__ float sr[8];
    int w = threadIdx.x >> 6;
    if ((threadIdx.x & 63) == 0) { sr[w] = s; sr[4 + w] = sq; }
    __syncthreads();
    if (threadIdx.x == 0) {
        atomicAdd(&part[b * 2], sr[0] + sr[1] + sr[2] + sr[3]);
        atomicAdd(&part[b * 2 + 1], sr[4] + sr[5] + sr[6] + sr[7]);
    }
}

// ------------------------------------------------- MFMA implicit-GEMM conv
// D[m=l][n=co] += sum_{tap,ci} X[l+tap-1][ci] * W[tap][co][ci]
// A frag: m=lane&15, k=(lane>>4)*8+j  (8 contiguous ci)
// B frag: n=lane&15, k=(lane>>4)*8+j
// C/D:    col(n)=lane&15, row(m)=(lane>>4)*4+reg
// MODE 0: relu -> bf16 channel-last out (h1)
// MODE 1: energy epilogue (op): xl=LN(in), nv=xl-0.1c-0.2relu(xl) -> hi/lo + stats
// MODE 2: relu -> fp32 channel-first out (h2, n<192 only)
template <int CHUNKS, int ICIP, int WCI, int COD, int CT, int MODE, bool SPLIT>
__global__ __launch_bounds__(256) void mfma_conv(
    const short* __restrict__ inh, const short* __restrict__ inl,
    const short* __restrict__ wh, const short* __restrict__ wl,
    const float* __restrict__ part_in, float* __restrict__ part_out,
    short* __restrict__ outh, short* __restrict__ outl,
    float* __restrict__ outf) {
    int bid = blockIdx.x;
    int ct = bid % CT;
    int lt = (bid / CT) & 3;
    int b = bid / (CT * 4);
    int l0 = lt * 128, co0 = ct * 128;
    int lane = threadIdx.x & 63, w = threadIdx.x >> 6;
    int wm = w & 1, wn = w >> 1;
    int lane15 = lane & 15, q = lane >> 4;

    f32x4 acc[4][4];
    #pragma unroll
    for (int i = 0; i < 4; i++)
        #pragma unroll
        for (int j = 0; j < 4; j++) acc[i][j] = (f32x4){0.f, 0.f, 0.f, 0.f};

    const size_t rowbase = (size_t)b * LROWS + l0;  // +tap+m gives input row

    for (int kc = 0; kc < CHUNKS; kc++) {
        int ci0 = kc * 32;
        #pragma unroll
        for (int tap = 0; tap < 3; tap++) {
            bf16x8 ah[4], bh[4], al[4], bl[4];
            #pragma unroll
            for (int mt = 0; mt < 4; mt++) {
                size_t ao = (rowbase + wm * 64 + mt * 16 + lane15 + tap) * ICIP +
                            ci0 + q * 8;
                ah[mt] = *(const bf16x8*)(inh + ao);
                if (SPLIT) al[mt] = *(const bf16x8*)(inl + ao);
            }
            #pragma unroll
            for (int nt = 0; nt < 4; nt++) {
                size_t bo = ((size_t)tap * COD + co0 + wn * 64 + nt * 16 + lane15) *
                                WCI + ci0 + q * 8;
                bh[nt] = *(const bf16x8*)(wh + bo);
                if (SPLIT) bl[nt] = *(const bf16x8*)(wl + bo);
            }
            #pragma unroll
            for (int mt = 0; mt < 4; mt++)
                #pragma unroll
                for (int nt = 0; nt < 4; nt++) {
                    acc[mt][nt] = __builtin_amdgcn_mfma_f32_16x16x32_bf16(
                        ah[mt], bh[nt], acc[mt][nt], 0, 0, 0);
                    if (SPLIT) {
                        acc[mt][nt] = __builtin_amdgcn_mfma_f32_16x16x32_bf16(
                            ah[mt], bl[nt], acc[mt][nt], 0, 0, 0);
                        acc[mt][nt] = __builtin_amdgcn_mfma_f32_16x16x32_bf16(
                            al[mt], bh[nt], acc[mt][nt], 0, 0, 0);
                    }
                }
        }
    }

    if (MODE == 1) {
        float s_in = part_in[b * 2], sq_in = part_in[b * 2 + 1];
        float mu = s_in / (float)NPB;
        float var = sq_in / (float)NPB - mu * mu;
        float rs = rsqrtf(var + 1e-5f);
        float s = 0.f, sq = 0.f;
        #pragma unroll
        for (int mt = 0; mt < 4; mt++)
            #pragma unroll
            for (int nt = 0; nt < 4; nt++)
                #pragma unroll
                for (int r = 0; r < 4; r++) {
                    int m = wm * 64 + mt * 16 + q * 4 + r;
                    int n = co0 + wn * 64 + nt * 16 + lane15;
                    size_t idx = (rowbase + m + 1) * CIP + n;
                    float itv = __bfloat162float(*(const __hip_bfloat16*)&inh[idx]) +
                                __bfloat162float(*(const __hip_bfloat16*)&inl[idx]);
                    float xl = (itv - mu) * rs;
                    float nv = xl - 0.1f * acc[mt][nt][r] - 0.2f * fmaxf(xl, 0.f);
                    s += nv;
                    sq += nv * nv;
                    __hip_bfloat16 h = __float2bfloat16(nv);
                    float lo = nv - __bfloat162float(h);
                    outh[idx] = *(short*)&h;
                    __hip_bfloat16 l2 = __float2bfloat16(lo);
                    outl[idx] = *(short*)&l2;
                }
        #pragma unroll
        for (int off = 32; off > 0; off >>= 1) {
            s += __shfl_down(s, off);
            sq += __shfl_down(sq, off);
        }
        __shared__ float sr[8];
        if (lane == 0) { sr[w] = s; sr[4 + w] = sq; }
        __syncthreads();
        if (threadIdx.x == 0) {
            atomicAdd(&part_out[b * 2], sr[0] + sr[1] + sr[2] + sr[3]);
            atomicAdd(&part_out[b * 2 + 1], sr[4] + sr[5] + sr[6] + sr[7]);
        }
    } else if (MODE == 0) {
        #pragma unroll
        for (int mt = 0; mt < 4; mt++)
            #pragma unroll
            for (int nt = 0; nt < 4; nt++)
                #pragma unroll
                for (int r = 0; r < 4; r++) {
                    int m = wm * 64 + mt * 16 + q * 4 + r;
                    int n = co0 + wn * 64 + nt * 16 + lane15;
                    size_t idx = (rowbase + m + 1) * WW + n;
                    __hip_bfloat16 h = __float2bfloat16(fmaxf(acc[mt][nt][r], 0.f));
                    outh[idx] = *(short*)&h;
                }
    } else {  // MODE 2: fp32 channel-first, relu, n<192
        #pragma unroll
        for (int mt = 0; mt < 4; mt++)
            #pragma unroll
            for (int nt = 0; nt < 4; nt++) {
                int n = co0 + wn * 64 + nt * 16 + lane15;
                if (n < 192) {
                    int mbase = l0 + wm * 64 + mt * 16 + q * 4;
                    float4 v = make_float4(fmaxf(acc[mt][nt][0], 0.f),
                                           fmaxf(acc[mt][nt][1], 0.f),
                                           fmaxf(acc[mt][nt][2], 0.f),
                                           fmaxf(acc[mt][nt][3], 0.f));
                    *(float4*)(outf + ((size_t)b * 192 + n) * LL + mbase) = v;
                }
            }
    }
}

// Final 192->2 conv from a2 [32][192][512] fp32 channel-first.
__global__ __launch_bounds__(256) void h3_conv(const float* __restrict__ a2,
                                               const float* __restrict__ w3,
                                               float* __restrict__ out, int t) {
    __shared__ float ws3[2 * 192 * 3];
    int tid = threadIdx.x;
    for (int i = tid; i < 2 * 192 * 3; i += 256) ws3[i] = w3[i];
    __syncthreads();
    int b = blockIdx.x >> 2;
    int ch = tid & 1;
    int l = (blockIdx.x & 3) * 128 + (tid >> 1);
    const float* ab = a2 + (size_t)b * 192 * LL;
    const float* wc = ws3 + ch * 576;
    float a = 0.f;
    for (int c = 0; c < 192; c++) {
        float x0 = (l > 0) ? ab[c * LL + l - 1] : 0.f;
        float x1 = ab[c * LL + l];
        float x2 = (l < LL - 1) ? ab[c * LL + l + 1] : 0.f;
        a += wc[c * 3] * x0 + wc[c * 3 + 1] * x1 + wc[c * 3 + 2] * x2;
    }
    out[(((size_t)b * ITERS + t) * 2 + ch) * LL + l] = a;
}

extern "C" void kernel_launch(void* const* d_in, const int* in_sizes, int n_in,
                              void* d_out, int out_size, void* d_ws, size_t ws_size,
                              hipStream_t stream) {
    const float* x = (const float*)d_in[0];
    const float* proj_w = (const float*)d_in[2];
    const float* op_w = (const float*)d_in[3];
    const float* h1_w = (const float*)d_in[4];
    const float* h2_w = (const float*)d_in[5];
    const float* h3_w = (const float*)d_in[6];
    float* out = (float*)d_out;

    char* base = (char*)d_ws;
    size_t off = 0;
    auto alloc = [&](size_t bytes) {
        char* p = base + off;
        off += (bytes + 255) & ~(size_t)255;
        return p;
    };
    const size_t ITB = (size_t)BB * LROWS * CIP * 2;  // bf16 it buffer bytes
    short* itAh = (short*)alloc(ITB);
    short* itAl = (short*)alloc(ITB);
    short* itBh = (short*)alloc(ITB);
    short* itBl = (short*)alloc(ITB);
    short* a1 = (short*)alloc((size_t)BB * LROWS * WW * 2);
    float* a2 = (float*)alloc((size_t)BB * 192 * LL * 4);
    short* wOph = (short*)alloc((size_t)3 * 384 * CIP * 2);
    short* wOpl = (short*)alloc((size_t)3 * 384 * CIP * 2);
    short* wH1 = (short*)alloc((size_t)3 * 384 * 384 * 2);
    short* wH2 = (short*)alloc((size_t)3 * 256 * 384 * 2);
    float* part = (float*)alloc((size_t)(ITERS + 1) * 64 * 4);
    if (off > ws_size) return;

    wsplit_op<<<(3 * 384 * CIP + 255) / 256, 256, 0, stream>>>(op_w, wOph, wOpl);
    wsplit_h<<<(3 * 384 * 384 + 255) / 256, 256, 0, stream>>>(h1_w, wH1, 384, 384, 384);
    wsplit_h<<<(3 * 256 * 384 + 255) / 256, 256, 0, stream>>>(h2_w, wH2, 256, 384, 192);
    init_rows<<<BB * LROWS, 64, 0, stream>>>(x, itAh, itAl, itBh, itBl, a1);
    zero_part<<<5, 256, 0, stream>>>(part, (ITERS + 1) * 64);
    proj_relu<<<dim3(LL * WW / 256, BB), 256, 0, stream>>>(x, proj_w, itAh, itAl, part);

    short *ch = itAh, *cl = itAl, *nh = itBh, *nl = itBl;
    for (int t = 0; t < ITERS; t++) {
        // op conv (split, energy epilogue): cur -> nxt, stats -> part[t+1]
        mfma_conv<13, CIP, CIP, 384, 3, 1, true><<<BB * 4 * 3, 256, 0, stream>>>(
            ch, cl, wOph, wOpl, part + t * 64, part + (t + 1) * 64, nh, nl, nullptr);
        // h1: nxt_hi -> a1 (bf16 channel-last, relu)
        mfma_conv<12, CIP, 384, 384, 3, 0, false><<<BB * 4 * 3, 256, 0, stream>>>(
            nh, nullptr, wH1, nullptr, nullptr, nullptr, a1, nullptr, nullptr);
        // h2: a1 -> a2 (fp32 channel-first, relu)
        mfma_conv<12, 384, 384, 256, 2, 2, false><<<BB * 4 * 2, 256, 0, stream>>>(
            a1, nullptr, wH2, nullptr, nullptr, nullptr, nullptr, nullptr, a2);
        h3_conv<<<BB * 4, 256, 0, stream>>>(a2, h3_w, out, t);
        short* th = ch; ch = nh; nh = th;
        short* tl = cl; cl = nl; nl = tl;
    }
}

// Round 4
// 2799.690 us; speedup vs baseline: 4.0165x; 1.5165x over previous
//
#include <hip/hip_runtime.h>
#include <hip/hip_bf16.h>

#define BB 32
#define WW 384
#define LL 512
#define ITERS 16
#define NPB (WW * LL)
#define LROWS 514           // 1 + 512 + 1 halo rows
#define CIP 416             // padded ci for it buffers (13 K-chunks of 32)

typedef __attribute__((ext_vector_type(8))) short bf16x8;
typedef __attribute__((ext_vector_type(4))) float f32x4;

__device__ __forceinline__ float b2f(short s) {
    unsigned u = ((unsigned)(unsigned short)s) << 16;
    float f;
    __builtin_memcpy(&f, &u, 4);
    return f;
}

__device__ __forceinline__ void gload_lds16(const void* g, void* l) {
    __builtin_amdgcn_global_load_lds(
        (const __attribute__((address_space(1))) void*)g,
        (__attribute__((address_space(3))) void*)l, 16, 0, 0);
}

// ---------------------------------------------------------------- prep
__global__ void wsplit_op(const float* __restrict__ w, short* __restrict__ wh,
                          short* __restrict__ wl) {
    int i = blockIdx.x * 256 + threadIdx.x;
    if (i >= 3 * 384 * CIP) return;
    int ci = i % CIP, co = (i / CIP) % 384, tap = i / (CIP * 384);
    float v = (ci < 385) ? w[(co * 385 + ci) * 3 + tap] : 0.f;
    __hip_bfloat16 h = __float2bfloat16(v);
    float lo = v - __bfloat162float(h);
    ((__hip_bfloat16*)wh)[i] = h;
    ((__hip_bfloat16*)wl)[i] = __float2bfloat16(lo);
}

__global__ void wsplit_h(const float* __restrict__ w, short* __restrict__ wh,
                         int COD, int CIN, int CO_real) {
    int i = blockIdx.x * 256 + threadIdx.x;
    if (i >= 3 * COD * CIN) return;
    int ci = i % CIN, co = (i / CIN) % COD, tap = i / (CIN * COD);
    float v = (co < CO_real) ? w[(co * CIN + ci) * 3 + tap] : 0.f;
    ((__hip_bfloat16*)wh)[i] = __float2bfloat16(v);
}

// zero halo rows of it buffers + a1 + a2; write x (hi/lo) into channel 384
// of both it ping-pong buffers, zero channels 385..415 (interior rows).
__global__ void init_rows(const float* __restrict__ x, short* itAh, short* itAl,
                          short* itBh, short* itBl, short* a1, short* a2) {
    int row = blockIdx.x % LROWS, b = blockIdx.x / LROWS;
    int tid = threadIdx.x;
    size_t base = ((size_t)b * LROWS + row) * CIP;
    size_t base1 = ((size_t)b * LROWS + row) * WW;
    size_t base2 = ((size_t)b * LROWS + row) * 192;
    if (row == 0 || row == LROWS - 1) {
        for (int i = tid; i < CIP; i += 64) {
            itAh[base + i] = 0; itAl[base + i] = 0;
            itBh[base + i] = 0; itBl[base + i] = 0;
        }
        for (int i = tid; i < WW; i += 64) a1[base1 + i] = 0;
        for (int i = tid; i < 192; i += 64) a2[base2 + i] = 0;
    } else {
        if (tid < 32) {
            int ci = WW + tid;
            short h = 0, l = 0;
            if (ci == WW) {
                float xv = x[b * LL + row - 1];
                __hip_bfloat16 xh = __float2bfloat16(xv);
                float xlo = xv - __bfloat162float(xh);
                h = *(short*)&xh;
                __hip_bfloat16 xl2 = __float2bfloat16(xlo);
                l = *(short*)&xl2;
            }
            itAh[base + ci] = h; itAl[base + ci] = l;
            itBh[base + ci] = h; itBl[base + ci] = l;
        }
    }
}

__global__ void zero_part(float* part, int n) {
    int i = blockIdx.x * 256 + threadIdx.x;
    if (i < n) part[i] = 0.f;
}

// it0 = relu(conv1d(x, proj_w)) + LN stats. 256 blocks (32 b x 8 slices) ->
// only 8 atomics per address (round-3 version had 768: 400 us serialization).
__global__ __launch_bounds__(256) void proj_relu(const float* __restrict__ x,
                                                 const float* __restrict__ wp,
                                                 short* __restrict__ oh,
                                                 short* __restrict__ ol,
                                                 float* __restrict__ part) {
    int b = blockIdx.x >> 3, sl = blockIdx.x & 7;
    int tid = threadIdx.x;
    __shared__ float ws[WW * 3];
    __shared__ float xs[66];
    for (int i = tid; i < WW * 3; i += 256) ws[i] = wp[i];
    int l0 = sl * 64;
    for (int i = tid; i < 66; i += 256) {
        int l = l0 + i - 1;
        xs[i] = (l >= 0 && l < LL) ? x[b * LL + l] : 0.f;
    }
    __syncthreads();
    float s = 0.f, sq = 0.f;
    for (int idx = tid; idx < 64 * WW; idx += 256) {
        int lo = idx / WW, co = idx % WW;
        float v = fmaxf(ws[co * 3] * xs[lo] + ws[co * 3 + 1] * xs[lo + 1] +
                            ws[co * 3 + 2] * xs[lo + 2], 0.f);
        size_t o = ((size_t)b * LROWS + l0 + lo + 1) * CIP + co;
        __hip_bfloat16 h = __float2bfloat16(v);
        float lof = v - __bfloat162float(h);
        oh[o] = *(short*)&h;
        __hip_bfloat16 l2 = __float2bfloat16(lof);
        ol[o] = *(short*)&l2;
        s += v; sq += v * v;
    }
    #pragma unroll
    for (int off = 32; off > 0; off >>= 1) {
        s += __shfl_down(s, off);
        sq += __shfl_down(sq, off);
    }
    __shared__ float sr[8];
    int w = tid >> 6;
    if ((tid & 63) == 0) { sr[w] = s; sr[4 + w] = sq; }
    __syncthreads();
    if (tid == 0) {
        atomicAdd(&part[b * 2], sr[0] + sr[1] + sr[2] + sr[3]);
        atomicAdd(&part[b * 2 + 1], sr[4] + sr[5] + sr[6] + sr[7]);
    }
}

// ------------------------------------------------- MFMA implicit-GEMM conv
// Tile (MT*32)l x 64co per block, 2 waves split along l (wave tile MT*16 x 64).
// A-tile (hi[/lo]) staged in LDS via global_load_lds (width 16); layout:
// section s = hl*4 + q holds ci sub-range q*8..q*8+7 for rows 0..R-1, 16 B/row
// (lane==row for staging insts). B (weights) read direct from global (L1/L2).
// MODE 0: relu -> bf16 channel-last out (stride OST, interior rows).
// MODE 1: energy epilogue: xl=LN(in), nv=xl-0.1c-0.2relu(xl) -> hi/lo + stats.
template <int CHUNKS, int ICIP, int WCI, int COD, int CT, int MT, int MODE,
          bool SPLIT, int OST>
__global__ __launch_bounds__(128) void mfma_conv(
    const short* __restrict__ inh, const short* __restrict__ inl,
    const short* __restrict__ wh, const short* __restrict__ wl,
    const float* __restrict__ part_in, float* __restrict__ part_out,
    short* __restrict__ outh, short* __restrict__ outl) {
    constexpr int LT = 512 / (MT * 32);
    constexpr int R = MT * 32 + 2;      // staged rows (tile + 2 halo)
    constexpr int RA = MT * 32 + 4;     // allocated rows per section
    constexpr int SEC = RA * 8;         // section stride in shorts (16 B/row)
    constexpr int NS = SPLIT ? 8 : 4;   // sections (4 ci-octets x hi/lo)
    constexpr int NI = (R + 63) / 64;   // staging insts per section

    int bid = blockIdx.x;
    int ct = bid % CT;
    int lt = (bid / CT) % LT;
    int b = bid / (CT * LT);
    int l0 = lt * (MT * 32), co0 = ct * 64;
    int tid = threadIdx.x;
    int lane = tid & 63, w = tid >> 6;
    int lane15 = lane & 15, q = lane >> 4;
    int wmbase = w * MT * 16;
    const size_t rowbase = (size_t)b * LROWS + l0;

    __shared__ short As[NS * SEC];

    f32x4 acc[MT][4];
    #pragma unroll
    for (int i = 0; i < MT; i++)
        #pragma unroll
        for (int j = 0; j < 4; j++) acc[i][j] = (f32x4){0.f, 0.f, 0.f, 0.f};

    for (int kc = 0; kc < CHUNKS; kc++) {
        int ci0 = kc * 32;
        // ---- stage A chunk into LDS (waves split the NS*NI insts)
        for (int item = w; item < NS * NI; item += 2) {
            int s = item / NI, i = item % NI;
            int qq = s & 3;
            const short* src = (SPLIT && (s >> 2)) ? inl : inh;
            int row = i * 64 + lane;
            if (row < R)
                gload_lds16(src + (rowbase + row) * ICIP + ci0 + qq * 8,
                            &As[s * SEC + i * 64 * 8]);
        }
        __syncthreads();
        #pragma unroll
        for (int tap = 0; tap < 3; tap++) {
            bf16x8 ah[MT], al[MT], bh[4], bl[4];
            #pragma unroll
            for (int mt = 0; mt < MT; mt++) {
                int row = wmbase + mt * 16 + lane15 + tap;
                const short* ap = &As[q * SEC + row * 8];
                ah[mt] = *(const bf16x8*)ap;
                if (SPLIT) al[mt] = *(const bf16x8*)(ap + 4 * SEC);
            }
            #pragma unroll
            for (int nt = 0; nt < 4; nt++) {
                size_t bo = ((size_t)(tap * COD + co0 + nt * 16 + lane15)) * WCI +
                            ci0 + q * 8;
                bh[nt] = *(const bf16x8*)(wh + bo);
                if (SPLIT) bl[nt] = *(const bf16x8*)(wl + bo);
            }
            #pragma unroll
            for (int mt = 0; mt < MT; mt++)
                #pragma unroll
                for (int nt = 0; nt < 4; nt++) {
                    acc[mt][nt] = __builtin_amdgcn_mfma_f32_16x16x32_bf16(
                        ah[mt], bh[nt], acc[mt][nt], 0, 0, 0);
                    if (SPLIT) {
                        acc[mt][nt] = __builtin_amdgcn_mfma_f32_16x16x32_bf16(
                            ah[mt], bl[nt], acc[mt][nt], 0, 0, 0);
                        acc[mt][nt] = __builtin_amdgcn_mfma_f32_16x16x32_bf16(
                            al[mt], bh[nt], acc[mt][nt], 0, 0, 0);
                    }
                }
        }
        __syncthreads();
    }

    if (MODE == 1) {
        float s_in = part_in[b * 2], sq_in = part_in[b * 2 + 1];
        float mu = s_in / (float)NPB;
        float var = sq_in / (float)NPB - mu * mu;
        float rs = rsqrtf(var + 1e-5f);
        float s = 0.f, sq = 0.f;
        #pragma unroll
        for (int mt = 0; mt < MT; mt++)
            #pragma unroll
            for (int nt = 0; nt < 4; nt++)
                #pragma unroll
                for (int r = 0; r < 4; r++) {
                    int m = wmbase + mt * 16 + q * 4 + r;
                    int n = co0 + nt * 16 + lane15;
                    size_t idx = (rowbase + m + 1) * ICIP + n;
                    float itv = b2f(inh[idx]) + b2f(inl[idx]);
                    float xl = (itv - mu) * rs;
                    float nv = xl - 0.1f * acc[mt][nt][r] - 0.2f * fmaxf(xl, 0.f);
                    s += nv;
                    sq += nv * nv;
                    __hip_bfloat16 h = __float2bfloat16(nv);
                    float lo = nv - __bfloat162float(h);
                    outh[idx] = *(short*)&h;
                    __hip_bfloat16 l2 = __float2bfloat16(lo);
                    outl[idx] = *(short*)&l2;
                }
        #pragma unroll
        for (int off = 32; off > 0; off >>= 1) {
            s += __shfl_down(s, off);
            sq += __shfl_down(sq, off);
        }
        __shared__ float sr[4];
        if (lane == 0) { sr[w] = s; sr[2 + w] = sq; }
        __syncthreads();
        if (tid == 0) {
            atomicAdd(&part_out[b * 2], sr[0] + sr[1]);
            atomicAdd(&part_out[b * 2 + 1], sr[2] + sr[3]);
        }
    } else {
        #pragma unroll
        for (int mt = 0; mt < MT; mt++)
            #pragma unroll
            for (int nt = 0; nt < 4; nt++)
                #pragma unroll
                for (int r = 0; r < 4; r++) {
                    int m = wmbase + mt * 16 + q * 4 + r;
                    int n = co0 + nt * 16 + lane15;
                    size_t idx = (rowbase + m + 1) * OST + n;
                    __hip_bfloat16 h = __float2bfloat16(fmaxf(acc[mt][nt][r], 0.f));
                    outh[idx] = *(short*)&h;
                }
    }
}

// Final 192->2 conv from a2 [32][514][192] bf16 channel-last (halo-padded).
__global__ __launch_bounds__(128) void h3_conv(const short* __restrict__ a2,
                                               const float* __restrict__ w3,
                                               float* __restrict__ out, int t) {
    __shared__ float ws3[2 * 192 * 3];
    int tid = threadIdx.x;
    for (int i = tid; i < 2 * 192 * 3; i += 128) ws3[i] = w3[i];
    __syncthreads();
    int b = blockIdx.x >> 3, sl = blockIdx.x & 7;
    int l = sl * 64 + (tid >> 1);
    int ch = tid & 1;
    const short* r0 = a2 + ((size_t)b * LROWS + l) * 192;  // buffer row l = l-1
    const float* wc = ws3 + ch * 576;
    float a = 0.f;
    #pragma unroll 4
    for (int c8 = 0; c8 < 24; c8++) {
        bf16x8 v0 = *(const bf16x8*)(r0 + c8 * 8);
        bf16x8 v1 = *(const bf16x8*)(r0 + 192 + c8 * 8);
        bf16x8 v2 = *(const bf16x8*)(r0 + 384 + c8 * 8);
        #pragma unroll
        for (int j = 0; j < 8; j++) {
            const float* wp = wc + (c8 * 8 + j) * 3;
            a += wp[0] * b2f(v0[j]) + wp[1] * b2f(v1[j]) + wp[2] * b2f(v2[j]);
        }
    }
    out[(((size_t)b * ITERS + t) * 2 + ch) * LL + l] = a;
}

extern "C" void kernel_launch(void* const* d_in, const int* in_sizes, int n_in,
                              void* d_out, int out_size, void* d_ws, size_t ws_size,
                              hipStream_t stream) {
    const float* x = (const float*)d_in[0];
    const float* proj_w = (const float*)d_in[2];
    const float* op_w = (const float*)d_in[3];
    const float* h1_w = (const float*)d_in[4];
    const float* h2_w = (const float*)d_in[5];
    const float* h3_w = (const float*)d_in[6];
    float* out = (float*)d_out;

    char* base = (char*)d_ws;
    size_t off = 0;
    auto alloc = [&](size_t bytes) {
        char* p = base + off;
        off += (bytes + 255) & ~(size_t)255;
        return p;
    };
    const size_t ITB = (size_t)BB * LROWS * CIP * 2;
    short* itAh = (short*)alloc(ITB);
    short* itAl = (short*)alloc(ITB);
    short* itBh = (short*)alloc(ITB);
    short* itBl = (short*)alloc(ITB);
    short* a1 = (short*)alloc((size_t)BB * LROWS * WW * 2);
    short* a2 = (short*)alloc((size_t)BB * LROWS * 192 * 2);
    short* wOph = (short*)alloc((size_t)3 * 384 * CIP * 2);
    short* wOpl = (short*)alloc((size_t)3 * 384 * CIP * 2);
    short* wH1 = (short*)alloc((size_t)3 * 384 * 384 * 2);
    short* wH2 = (short*)alloc((size_t)3 * 256 * 384 * 2);
    float* part = (float*)alloc((size_t)(ITERS + 1) * 64 * 4);
    if (off > ws_size) return;

    wsplit_op<<<(3 * 384 * CIP + 255) / 256, 256, 0, stream>>>(op_w, wOph, wOpl);
    wsplit_h<<<(3 * 384 * 384 + 255) / 256, 256, 0, stream>>>(h1_w, wH1, 384, 384, 384);
    wsplit_h<<<(3 * 256 * 384 + 255) / 256, 256, 0, stream>>>(h2_w, wH2, 256, 384, 192);
    init_rows<<<BB * LROWS, 64, 0, stream>>>(x, itAh, itAl, itBh, itBl, a1, a2);
    zero_part<<<5, 256, 0, stream>>>(part, (ITERS + 1) * 64);
    proj_relu<<<BB * 8, 256, 0, stream>>>(x, proj_w, itAh, itAl, part);

    short *ch = itAh, *cl = itAl, *nh = itBh, *nl = itBl;
    for (int t = 0; t < ITERS; t++) {
        // op conv (split, energy epilogue): cur -> nxt, stats -> part[t+1]
        mfma_conv<13, CIP, CIP, 384, 6, 4, 1, true, CIP>
            <<<BB * 4 * 6, 128, 0, stream>>>(ch, cl, wOph, wOpl, part + t * 64,
                                             part + (t + 1) * 64, nh, nl);
        // h1: nxt_hi -> a1 (bf16 channel-last, relu)
        mfma_conv<12, CIP, 384, 384, 6, 4, 0, false, WW>
            <<<BB * 4 * 6, 128, 0, stream>>>(nh, nullptr, wH1, nullptr, nullptr,
                                             nullptr, a1, nullptr);
        // h2: a1 -> a2 (bf16 channel-last, relu), 192 couts (CT=3)
        mfma_conv<12, WW, 384, 256, 3, 2, 0, false, 192>
            <<<BB * 8 * 3, 128, 0, stream>>>(a1, nullptr, wH2, nullptr, nullptr,
                                             nullptr, a2, nullptr);
        h3_conv<<<BB * 8, 128, 0, stream>>>(a2, h3_w, out, t);
        short* th = ch; ch = nh; nh = th;
        short* tl = cl; cl = nl; nl = tl;
    }
}